// Round 3
// baseline (632.149 us; speedup 1.0000x reference)
//
#include <hip/hip_runtime.h>
#include <hip/hip_bf16.h>
#include <stdint.h>

// BitNet b1.58 linear: out[M,N] = x[M,K] @ (ternary(W)*scale)[N,K]^T + bias[N]
// M=8192, N=4096, K=4096.
//
// R2 -> R3:
//  * prepass: removed the serialized same-address fp64 atomicAdd (suspected
//    ~100+ us); two-pass tree reduction instead. quant/xcvt back to clean
//    1-float4-load + 1-ushort4-store per thread.
//  * GEMM: BK=32 double-buffered K-loop, ONE barrier per iteration, prefetch
//    DMA issued right after the barrier into the opposite buffer -> the
//    compiler's vmcnt(0) drain at the barrier waits on loads issued a full
//    iteration earlier (near-free). LDS stays 32 KB total.
//    Swizzle: LDS slot of 16B chunk g in row r is g^(r&3); fragment read
//    slot = lk^(lm&3) -> every bank hit exactly 8x per wave read (minimum).

#define BM 128
#define BN 128
#define BK 32

typedef __bf16 bf16x8 __attribute__((ext_vector_type(8)));
typedef float f32x4 __attribute__((ext_vector_type(4)));

__device__ __forceinline__ unsigned short f2bf_rne(float f) {
  union { float f; unsigned int u; } v; v.f = f;
  unsigned int u = v.u;
  u += 0x7FFFu + ((u >> 16) & 1u);
  return (unsigned short)(u >> 16);
}

// ------------------------------------------------------------ reduction p1
// 256 blocks -> 256 fp32 partials (no atomics).
__global__ void absum_p1(const float4* __restrict__ w, int n4,
                         float* __restrict__ partials) {
  float s = 0.f;
  for (int i = blockIdx.x * blockDim.x + threadIdx.x; i < n4;
       i += gridDim.x * blockDim.x) {
    float4 v = w[i];
    s += fabsf(v.x) + fabsf(v.y) + fabsf(v.z) + fabsf(v.w);
  }
#pragma unroll
  for (int o = 32; o > 0; o >>= 1) s += __shfl_down(s, o);
  __shared__ float p[4];
  if ((threadIdx.x & 63) == 0) p[threadIdx.x >> 6] = s;
  __syncthreads();
  if (threadIdx.x == 0) partials[blockIdx.x] = p[0] + p[1] + p[2] + p[3];
}

// ------------------------------------------------------------ reduction p2
// 1 block: fp64 tree over 256 partials -> clamped scale (float) in ws.
__global__ void absum_p2(const float* __restrict__ partials, int n,
                         double inv_cnt, float* __restrict__ scale_out) {
  double s = (threadIdx.x < n) ? (double)partials[threadIdx.x] : 0.0;
#pragma unroll
  for (int o = 32; o > 0; o >>= 1) s += __shfl_down(s, o);
  __shared__ double p[4];
  if ((threadIdx.x & 63) == 0) p[threadIdx.x >> 6] = s;
  __syncthreads();
  if (threadIdx.x == 0) {
    double m = (p[0] + p[1] + p[2] + p[3]) * inv_cnt;
    scale_out[0] = (float)fmin(fmax(m, 1e-5), 1000.0);
  }
}

// ---------------------------------------------------------------- quantize W
__global__ void quant_kernel(const float4* __restrict__ w, int n4,
                             const float* __restrict__ scale_p,
                             ushort4* __restrict__ q) {
  const float scale = scale_p[0];
  const float T = 2.0f / 3.0f;
  for (int i = blockIdx.x * blockDim.x + threadIdx.x; i < n4;
       i += gridDim.x * blockDim.x) {
    float4 v = w[i];
    ushort4 o;
    float nx = v.x / scale, ny = v.y / scale, nz = v.z / scale, nw = v.w / scale;
    o.x = (nx > T) ? 0x3F80u : ((nx < -T) ? 0xBF80u : 0u);
    o.y = (ny > T) ? 0x3F80u : ((ny < -T) ? 0xBF80u : 0u);
    o.z = (nz > T) ? 0x3F80u : ((nz < -T) ? 0xBF80u : 0u);
    o.w = (nw > T) ? 0x3F80u : ((nw < -T) ? 0xBF80u : 0u);
    q[i] = o;
  }
}

// ---------------------------------------------------------------- x -> bf16
__global__ void xcvt_kernel(const float4* __restrict__ x, int n4,
                            ushort4* __restrict__ xb) {
  for (int i = blockIdx.x * blockDim.x + threadIdx.x; i < n4;
       i += gridDim.x * blockDim.x) {
    float4 v = x[i];
    ushort4 o;
    o.x = f2bf_rne(v.x);
    o.y = f2bf_rne(v.y);
    o.z = f2bf_rne(v.z);
    o.w = f2bf_rne(v.w);
    xb[i] = o;
  }
}

// ---------------------------------------------------------------- GEMM
__global__ __launch_bounds__(256) void gemm_kernel(
    const ushort* __restrict__ xb,   // [M,K] bf16 bits
    const ushort* __restrict__ qb,   // [N,K] bf16 bits
    const float* __restrict__ bias,  // [N]
    const float* __restrict__ scale_p,
    float* __restrict__ out,         // [M,N]
    int M, int N, int K) {
  __shared__ __align__(16) ushort As[2][BM * BK];
  __shared__ __align__(16) ushort Bs[2][BN * BK];

  const int t = threadIdx.x;
  const int wave = t >> 6;
  const int lane = t & 63;
  const int m0 = blockIdx.y * BM;
  const int n0 = blockIdx.x * BN;

  const int wr = (wave >> 1) * 64;  // wave's m-offset in tile
  const int wc = (wave & 1) * 64;   // wave's n-offset in tile
  const int lm = lane & 15;
  const int lk = lane >> 4;

  // staging: rows of BK=32 elems = 4 chunks of 8. lane l -> row l>>2,
  // LDS slot l&3, which must carry global chunk (l&3)^((l>>2)&3).
  const int srow = lane >> 2;              // 0..15
  const int gchunk = (lane & 3) ^ (srow & 3);
  const ushort* ag = xb + (size_t)(m0 + wave * 32 + srow) * K + gchunk * 8;
  const ushort* bg = qb + (size_t)(n0 + wave * 32 + srow) * K + gchunk * 8;
  const int lbase = (wave * 32) * BK;      // wave-uniform LDS elem offset

  f32x4 acc[4][4] = {};

  // prologue: stage tile 0 into buffer 0
#pragma unroll
  for (int s = 0; s < 2; ++s) {
    __builtin_amdgcn_global_load_lds(
        (const __attribute__((address_space(1))) void*)(ag + (size_t)s * 16 * K),
        (__attribute__((address_space(3))) void*)(&As[0][lbase + s * 16 * BK]),
        16, 0, 0);
    __builtin_amdgcn_global_load_lds(
        (const __attribute__((address_space(1))) void*)(bg + (size_t)s * 16 * K),
        (__attribute__((address_space(3))) void*)(&Bs[0][lbase + s * 16 * BK]),
        16, 0, 0);
  }
  ag += BK;
  bg += BK;

  int par = 0;
  for (int k0 = 0; k0 < K; k0 += BK) {
    __syncthreads();  // drains the (iteration-old) DMA for buf[par]
    if (k0 + BK < K) {
      const int nxt = par ^ 1;
#pragma unroll
      for (int s = 0; s < 2; ++s) {
        __builtin_amdgcn_global_load_lds(
            (const __attribute__((address_space(1))) void*)(ag + (size_t)s * 16 * K),
            (__attribute__((address_space(3))) void*)(&As[nxt][lbase + s * 16 * BK]),
            16, 0, 0);
        __builtin_amdgcn_global_load_lds(
            (const __attribute__((address_space(1))) void*)(bg + (size_t)s * 16 * K),
            (__attribute__((address_space(3))) void*)(&Bs[nxt][lbase + s * 16 * BK]),
            16, 0, 0);
      }
      ag += BK;
      bg += BK;
    }

    bf16x8 af[4], bf[4];
#pragma unroll
    for (int i = 0; i < 4; ++i) {
      const int row = wr + i * 16 + lm;
      const int slot = lk ^ (row & 3);
      af[i] = *(const bf16x8*)&As[par][row * BK + slot * 8];
    }
#pragma unroll
    for (int j = 0; j < 4; ++j) {
      const int row = wc + j * 16 + lm;
      const int slot = lk ^ (row & 3);
      bf[j] = *(const bf16x8*)&Bs[par][row * BK + slot * 8];
    }
#pragma unroll
    for (int i = 0; i < 4; ++i)
#pragma unroll
      for (int j = 0; j < 4; ++j)
        acc[i][j] = __builtin_amdgcn_mfma_f32_16x16x32_bf16(af[i], bf[j],
                                                            acc[i][j], 0, 0, 0);
    par ^= 1;
  }

  const float scale = scale_p[0];

  // C/D layout (m89-verified): col = lane&15, row = (lane>>4)*4 + reg
#pragma unroll
  for (int j = 0; j < 4; ++j) {
    const int col = n0 + wc + j * 16 + lm;
    const float bv = bias[col];
#pragma unroll
    for (int i = 0; i < 4; ++i) {
      const int row = m0 + wr + i * 16 + lk * 4;
      float* op = out + (size_t)row * N + col;
#pragma unroll
      for (int r = 0; r < 4; ++r)
        op[(size_t)r * N] = acc[i][j][r] * scale + bv;
    }
  }
}

// ---------------------------------------------------------------- launch
extern "C" void kernel_launch(void* const* d_in, const int* in_sizes, int n_in,
                              void* d_out, int out_size, void* d_ws,
                              size_t ws_size, hipStream_t stream) {
  const float* x = (const float*)d_in[0];
  const float* w = (const float*)d_in[1];
  const float* bias = (const float*)d_in[2];
  float* out = (float*)d_out;

  const int DOUT = in_sizes[2];        // 4096
  const int DIN = in_sizes[1] / DOUT;  // 4096
  const int M = in_sizes[0] / DIN;     // 8192
  const int N = DOUT, K = DIN;

  char* ws = (char*)d_ws;
  float* scale_p = (float*)ws;                      // 4 B
  float* partials = (float*)(ws + 1024);            // 256 floats
  ushort* xb = (ushort*)(ws + 8192);                // M*K*2 B
  ushort* qb = (ushort*)(ws + 8192 + (size_t)M * K * 2);  // N*K*2 B

  const double inv_cnt = 1.0 / ((double)N * (double)K);

  const int wn4 = (N * K) / 4;
  absum_p1<<<256, 256, 0, stream>>>((const float4*)w, wn4, partials);
  absum_p2<<<1, 256, 0, stream>>>(partials, 256, inv_cnt, scale_p);
  quant_kernel<<<4096, 256, 0, stream>>>((const float4*)w, wn4, scale_p,
                                         (ushort4*)qb);
  const int xn4 = (M * K) / 4;
  xcvt_kernel<<<8192, 256, 0, stream>>>((const float4*)x, xn4, (ushort4*)xb);

  dim3 grid(N / BN, M / BM);
  gemm_kernel<<<grid, 256, 0, stream>>>(xb, qb, bias, scale_p, out, M, N, K);
}